// Round 3
// baseline (272.005 us; speedup 1.0000x reference)
//
#include <hip/hip_runtime.h>

typedef float vfloat4 __attribute__((ext_vector_type(4)));

// Kernel 1: E[b] = expm(t[b] * A), A = 0.5*(B - B^T), B = M + M0, 8x8.
// One block (64 threads) per t value; thread `lane` owns element (i,j).
// Taylor series to k=12: ||tA|| <~ 0.1 so this is exact to fp32 roundoff.
__global__ void expm_kernel(const float* __restrict__ M, const float* __restrict__ M0,
                            const float* __restrict__ t, float* __restrict__ E) {
    const int b = blockIdx.x;
    const int lane = threadIdx.x;            // 0..63
    const int i = lane >> 3;
    const int j = lane & 7;

    __shared__ float sA[64];                 // tA
    __shared__ float sP[64];                 // current Taylor term

    const float bij = M[i * 8 + j] + M0[i * 8 + j];
    const float bji = M[j * 8 + i] + M0[j * 8 + i];
    const float ta = t[b] * 0.5f * (bij - bji);

    sA[lane] = ta;
    float e = (i == j ? 1.0f : 0.0f) + ta;   // I + tA
    float p = ta;
    __syncthreads();

    for (int k = 2; k <= 12; ++k) {
        sP[lane] = p;
        __syncthreads();
        float s = 0.0f;
        #pragma unroll
        for (int l = 0; l < 8; ++l) {
            s = fmaf(sP[i * 8 + l], sA[l * 8 + j], s);
        }
        p = s * (1.0f / (float)k);
        e += p;
        __syncthreads();                     // protect sP before next overwrite
    }

    E[b * 64 + lane] = e;
}

// Kernel 2: out[t, n, i] = sum_j E[t][i][j] * x[n][j].
// One float4 of output per thread-iteration, LANE-CONTIGUOUS stores:
// thread handles out-float4 index k = base + g*256 + tid. Parity of k equals
// parity of tid (base and g*256 are even), so each thread statically owns one
// half of E (rows 4h..4h+3 == 32 contiguous floats), loaded once into VGPRs.
// Lane pairs (2m, 2m+1) load the same 32 B x row (L1-served redundancy).
// Stores are non-temporal: the 256 MiB out stream must not evict x from L2.
#define APPLY_G 8

__global__ __launch_bounds__(256) void apply_kernel(const float* __restrict__ Eall,
                                                    const float* __restrict__ x,
                                                    float* __restrict__ out,
                                                    int N) {
    const int t = blockIdx.y;
    const int tid = threadIdx.x;
    const int h = tid & 1;                   // which half of E this thread uses
    const int twoN = N * 2;                  // float4 count per t-slab

    // Load this thread's 32 E coefficients (rows 4h..4h+3, row-major).
    const float4* __restrict__ Ep = (const float4*)(Eall + t * 64 + h * 32);
    float eh[32];
    #pragma unroll
    for (int q = 0; q < 8; ++q) {
        const float4 v = Ep[q];
        eh[q * 4 + 0] = v.x; eh[q * 4 + 1] = v.y;
        eh[q * 4 + 2] = v.z; eh[q * 4 + 3] = v.w;
    }

    const int k0 = blockIdx.x * (256 * APPLY_G) + tid;
    const float4* __restrict__ x4 = (const float4*)x;
    vfloat4* __restrict__ o4 = (vfloat4*)out + (size_t)t * (size_t)twoN;

    #pragma unroll
    for (int g = 0; g < APPLY_G; ++g) {
        const int k = k0 + g * 256;          // out-float4 index in this t-slab
        if (k < twoN) {
            const int n = k >> 1;
            const float4 a = x4[2 * n];
            const float4 b = x4[2 * n + 1];
            const float xs[8] = {a.x, a.y, a.z, a.w, b.x, b.y, b.z, b.w};
            float y[4];
            #pragma unroll
            for (int r = 0; r < 4; ++r) {
                float s = 0.0f;
                #pragma unroll
                for (int jj = 0; jj < 8; ++jj) {
                    s = fmaf(eh[r * 8 + jj], xs[jj], s);
                }
                y[r] = s;
            }
            vfloat4 v = {y[0], y[1], y[2], y[3]};
            __builtin_nontemporal_store(v, &o4[k]);
        }
    }
}

extern "C" void kernel_launch(void* const* d_in, const int* in_sizes, int n_in,
                              void* d_out, int out_size, void* d_ws, size_t ws_size,
                              hipStream_t stream) {
    const float* x  = (const float*)d_in[0];   // [N, 8]
    const float* t  = (const float*)d_in[1];   // [T]
    const float* M  = (const float*)d_in[2];   // [8, 8]
    const float* M0 = (const float*)d_in[3];   // [8, 8]
    float* out = (float*)d_out;                // [T, N, 8]
    float* E = (float*)d_ws;                   // [T, 64] scratch (T*256 bytes)

    const int N = in_sizes[0] / 8;
    const int T = in_sizes[1];

    hipLaunchKernelGGL(expm_kernel, dim3(T), dim3(64), 0, stream, M, M0, t, E);

    const int gx = (N * 2 + 256 * APPLY_G - 1) / (256 * APPLY_G);
    hipLaunchKernelGGL(apply_kernel, dim3(gx, T), dim3(256), 0, stream, E, x, out, N);
}